// Round 1
// baseline (1910.222 us; speedup 1.0000x reference)
//
#include <hip/hip_runtime.h>
#include <cstdint>
#include <cstddef>

#define Hc   128      // hidden size
#define INc  256      // fmess feature dim
#define ZD   (INc + Hc)  // 384
#define Kc   8        // neighbors
#define TMr  8        // rows per workgroup
#define RPT  4        // rows per thread (TMr / 2 row-groups)

__device__ __forceinline__ float fsig(float x) {
  x = fminf(fmaxf(x, -30.f), 30.f);
  return 1.f / (1.f + __expf(-x));
}
__device__ __forceinline__ float ftanh(float x) {
  x = fminf(fmaxf(x, -15.f), 15.f);
  float e = __expf(2.f * x);
  return (e - 1.f) / (e + 1.f);
}

// ---------------- utility kernels ----------------

__global__ void copy_hc(const float4* __restrict__ h_in, const float4* __restrict__ c_in,
                        float4* __restrict__ h_out, float4* __restrict__ c_out, long n4) {
  long i = (long)blockIdx.x * blockDim.x + threadIdx.x;
  long stride = (long)gridDim.x * blockDim.x;
  for (; i < n4; i += stride) {
    h_out[i] = h_in[i];
    c_out[i] = c_in[i];
  }
}

__global__ void zero_f4(float4* __restrict__ p, long n4) {
  long i = (long)blockIdx.x * blockDim.x + threadIdx.x;
  long stride = (long)gridDim.x * blockDim.x;
  float4 z; z.x = z.y = z.z = z.w = 0.f;
  for (; i < n4; i += stride) p[i] = z;
}

__global__ void mark_init(int* __restrict__ mark, int M) {
  int i = blockIdx.x * blockDim.x + threadIdx.x;
  if (i < M) mark[i] = -1;
}

__global__ void mark_set(int* __restrict__ mark, const int* __restrict__ submess, int S) {
  int i = blockIdx.x * blockDim.x + threadIdx.x;
  if (i < S) mark[submess[i]] = i;
}

// ---------------- LSTM step ----------------
// One workgroup (256 threads) processes TMr=8 sub-rows.
// subH_src/subC_src == nullptr  =>  iteration 0 (sub state is zero).
// scatter_dst: 0 -> dst indexed by sub position i; 1 -> dst indexed by submess[i].
__global__ __launch_bounds__(256) void lstm_step(
    const float* __restrict__ fmess, const int* __restrict__ submess,
    const int* __restrict__ bgraph, const float* __restrict__ h_in,
    const float* __restrict__ c_in, const int* __restrict__ mark,
    const float* __restrict__ subH_src, const float* __restrict__ subC_src,
    const float* __restrict__ Wi, const float* __restrict__ bi,
    const float* __restrict__ Wo, const float* __restrict__ bo,
    const float* __restrict__ Wf, const float* __restrict__ bf,
    const float* __restrict__ Wu, const float* __restrict__ bu,
    float* __restrict__ dstH, float* __restrict__ dstC,
    int S, int scatter_dst)
{
  __shared__ __align__(16) float z[TMr][ZD];        // [x(256) | h_sum(128)]
  __shared__ __align__(16) float hn[TMr][Kc][Hc];   // gathered neighbor h
  __shared__ int nbj[TMr][Kc];
  __shared__ int nbm[TMr][Kc];
  __shared__ int msrow[TMr];

  const int t = threadIdx.x;
  const int row0 = blockIdx.x * TMr;

  // phase 1: sub-row ids
  if (t < TMr) {
    int s = row0 + t;
    msrow[t] = (s < S) ? submess[s] : -1;
  }
  __syncthreads();

  // phase 2: load x into z[:, 0:256]; resolve neighbor ids
  #pragma unroll
  for (int r = 0; r < TMr; ++r) {
    int ms = msrow[r];
    z[r][t] = (ms >= 0) ? fmess[(size_t)ms * INc + t] : 0.f;   // t in [0,256)
  }
  if (t < TMr * Kc) {
    int r = t >> 3, k = t & 7;
    int ms = msrow[r];
    int j = (ms >= 0) ? bgraph[(size_t)ms * Kc + k] : 0;
    nbj[r][k] = j;
    nbm[r][k] = (ms >= 0) ? mark[j] : -1;
  }
  __syncthreads();

  // phase 3: gather neighbor h
  const bool has_src = (subH_src != nullptr);
  for (int idx = t; idx < TMr * Kc * Hc; idx += 256) {
    int r = idx >> 10;            // /(Kc*Hc)=1024
    int k = (idx >> 7) & 7;
    int col = idx & 127;
    int ms = msrow[r];
    float v = 0.f;
    if (ms >= 0) {
      int m = nbm[r][k];
      if (m >= 0) v = has_src ? subH_src[(size_t)m * Hc + col] : 0.f;
      else        v = h_in[(size_t)nbj[r][k] * Hc + col];
    }
    hn[r][k][col] = v;
  }
  __syncthreads();

  // phase 4: h_sum into z[:, 256:384]
  for (int idx = t; idx < TMr * Hc; idx += 256) {
    int r = idx >> 7, col = idx & 127;
    float s = 0.f;
    #pragma unroll
    for (int k = 0; k < Kc; ++k) s += hn[r][k][col];
    z[r][INc + col] = s;
  }
  __syncthreads();

  // phase 5: fused gate GEMVs. thread -> (col, row-group of 4 rows)
  const int col = t & (Hc - 1);
  const int rg  = t >> 7;
  const int r0  = rg * RPT;

  float ai[RPT], ao[RPT], au[RPT], afx[RPT];
  {
    float bi_v = bi[col], bo_v = bo[col], bu_v = bu[col], bf_v = bf[col];
    #pragma unroll
    for (int r = 0; r < RPT; ++r) { ai[r] = bi_v; ao[r] = bo_v; au[r] = bu_v; afx[r] = bf_v; }
  }

  const float* Wi_c = Wi + col;
  const float* Wo_c = Wo + col;
  const float* Wu_c = Wu + col;
  const float* Wf_c = Wf + col;

  for (int kk = 0; kk < INc; kk += 4) {
    float4 zr[RPT];
    #pragma unroll
    for (int r = 0; r < RPT; ++r) zr[r] = *(const float4*)&z[r0 + r][kk];
    #pragma unroll
    for (int u = 0; u < 4; ++u) {
      const int w = (kk + u) * Hc;
      float wi = Wi_c[w], wo = Wo_c[w], wu = Wu_c[w], wf = Wf_c[w];
      #pragma unroll
      for (int r = 0; r < RPT; ++r) {
        float zv = (&zr[r].x)[u];
        ai[r]  = fmaf(zv, wi, ai[r]);
        ao[r]  = fmaf(zv, wo, ao[r]);
        au[r]  = fmaf(zv, wu, au[r]);
        afx[r] = fmaf(zv, wf, afx[r]);
      }
    }
  }
  for (int kk = INc; kk < ZD; kk += 4) {
    float4 zr[RPT];
    #pragma unroll
    for (int r = 0; r < RPT; ++r) zr[r] = *(const float4*)&z[r0 + r][kk];
    #pragma unroll
    for (int u = 0; u < 4; ++u) {
      const int w = (kk + u) * Hc;
      float wi = Wi_c[w], wo = Wo_c[w], wu = Wu_c[w];
      #pragma unroll
      for (int r = 0; r < RPT; ++r) {
        float zv = (&zr[r].x)[u];
        ai[r] = fmaf(zv, wi, ai[r]);
        ao[r] = fmaf(zv, wo, ao[r]);
        au[r] = fmaf(zv, wu, au[r]);
      }
    }
  }

  // phase 6: c = i*u (start), per-neighbor forget gates (kk-outer; Wf2 read once)
  float cacc[RPT], fo[RPT];
  #pragma unroll
  for (int r = 0; r < RPT; ++r) {
    cacc[r] = fsig(ai[r]) * ftanh(au[r]);
    fo[r] = ao[r];
  }

  float af[Kc][RPT];
  #pragma unroll
  for (int k = 0; k < Kc; ++k)
    #pragma unroll
    for (int r = 0; r < RPT; ++r) af[k][r] = afx[r];

  const float* Wf2_c = Wf + (size_t)INc * Hc + col;
  for (int kk = 0; kk < Hc; kk += 4) {
    float wfv[4];
    #pragma unroll
    for (int u = 0; u < 4; ++u) wfv[u] = Wf2_c[(kk + u) * Hc];
    #pragma unroll
    for (int k = 0; k < Kc; ++k) {
      float4 hr[RPT];
      #pragma unroll
      for (int r = 0; r < RPT; ++r) hr[r] = *(const float4*)&hn[r0 + r][k][kk];
      #pragma unroll
      for (int u = 0; u < 4; ++u)
        #pragma unroll
        for (int r = 0; r < RPT; ++r)
          af[k][r] = fmaf((&hr[r].x)[u], wfv[u], af[k][r]);
    }
  }

  // phase 7: c += sum_k sigmoid(f) * c_nei
  #pragma unroll
  for (int k = 0; k < Kc; ++k) {
    #pragma unroll
    for (int r = 0; r < RPT; ++r) {
      int m = nbm[r0 + r][k];
      int j = nbj[r0 + r][k];
      float cv;
      if (m >= 0) cv = subC_src ? subC_src[(size_t)m * Hc + col] : 0.f;
      else        cv = c_in[(size_t)j * Hc + col];
      cacc[r] = fmaf(fsig(af[k][r]), cv, cacc[r]);
    }
  }

  // phase 8: h = sigmoid(o) * tanh(c); write
  #pragma unroll
  for (int r = 0; r < RPT; ++r) {
    int ms = msrow[r0 + r];
    if (ms >= 0) {
      float cval = cacc[r];
      float hval = fsig(fo[r]) * ftanh(cval);
      size_t orow = scatter_dst ? (size_t)ms : (size_t)(row0 + r0 + r);
      dstH[orow * Hc + col] = hval;
      dstC[orow * Hc + col] = cval;
    }
  }
}

// ---------------- node readout ----------------
__global__ __launch_bounds__(256) void node_readout(
    const float* __restrict__ fnode, const int* __restrict__ agraph,
    const int* __restrict__ subnode, const float* __restrict__ hfull,
    const float* __restrict__ Wn, const float* __restrict__ bn,
    float* __restrict__ node_buf, int Nsub)
{
  __shared__ __align__(16) float z2[TMr][INc];   // [fnode(128) | nei_sum(128)]
  __shared__ int ag[TMr][Kc];
  __shared__ int orow[TMr];

  const int t = threadIdx.x;
  const int row0 = blockIdx.x * TMr;

  if (t < TMr) {
    int v = row0 + t;
    orow[t] = (v < Nsub) ? subnode[v] : -1;
  }
  if (t >= 64 && t < 64 + TMr * Kc) {
    int i = t - 64, r = i >> 3, k = i & 7;
    int v = row0 + r;
    ag[r][k] = (v < Nsub) ? agraph[(size_t)v * Kc + k] : 0;
  }
  __syncthreads();

  for (int idx = t; idx < TMr * Hc; idx += 256) {
    int r = idx >> 7, c = idx & 127;
    int v = row0 + r;
    z2[r][c] = (v < Nsub) ? fnode[(size_t)v * Hc + c] : 0.f;
    float s = 0.f;
    #pragma unroll
    for (int k = 0; k < Kc; ++k) s += hfull[(size_t)ag[r][k] * Hc + c];
    z2[r][Hc + c] = s;
  }
  __syncthreads();

  const int col = t & (Hc - 1);
  const int rg  = t >> 7;
  const int r0  = rg * RPT;

  float acc[RPT];
  {
    float bnv = bn[col];
    #pragma unroll
    for (int r = 0; r < RPT; ++r) acc[r] = bnv;
  }
  const float* Wn_c = Wn + col;
  for (int kk = 0; kk < INc; kk += 4) {
    float4 zr[RPT];
    #pragma unroll
    for (int r = 0; r < RPT; ++r) zr[r] = *(const float4*)&z2[r0 + r][kk];
    #pragma unroll
    for (int u = 0; u < 4; ++u) {
      float w = Wn_c[(kk + u) * Hc];
      #pragma unroll
      for (int r = 0; r < RPT; ++r)
        acc[r] = fmaf((&zr[r].x)[u], w, acc[r]);
    }
  }

  #pragma unroll
  for (int r = 0; r < RPT; ++r) {
    int o = orow[r0 + r];
    if (o >= 0) node_buf[(size_t)o * Hc + col] = fmaxf(acc[r], 0.f);
  }
}

// ---------------- launch ----------------
extern "C" void kernel_launch(void* const* d_in, const int* in_sizes, int n_in,
                              void* d_out, int out_size, void* d_ws, size_t ws_size,
                              hipStream_t stream) {
  const float* fnode   = (const float*)d_in[0];
  const float* fmess   = (const float*)d_in[1];
  const int*   agraph  = (const int*)d_in[2];
  const int*   bgraph  = (const int*)d_in[3];
  const float* h_in    = (const float*)d_in[4];
  const float* c_in    = (const float*)d_in[5];
  const int*   submess = (const int*)d_in[6];
  const int*   subnode = (const int*)d_in[7];
  // d_in[8] = num_nodes (device scalar; derived from out_size instead)
  const float* Wi = (const float*)d_in[9];
  const float* bi = (const float*)d_in[10];
  const float* Wo = (const float*)d_in[11];
  const float* bo = (const float*)d_in[12];
  const float* Wf = (const float*)d_in[13];
  const float* bf = (const float*)d_in[14];
  const float* Wu = (const float*)d_in[15];
  const float* bu = (const float*)d_in[16];
  const float* Wn = (const float*)d_in[17];
  const float* bn = (const float*)d_in[18];

  const int S    = in_sizes[6];
  const int Nsub = in_sizes[2] / Kc;
  const int M    = in_sizes[4] / Hc;
  const int num_nodes = out_size / Hc - 2 * M;

  float* node_buf = (float*)d_out;
  float* h_out = node_buf + (size_t)num_nodes * Hc;
  float* c_out = h_out + (size_t)M * Hc;

  // workspace: mark[M] ints, then compact sub_c scratch [S, H].
  // compact sub_h scratch lives in the node_buf region (unused until zeroed).
  int* mark = (int*)d_ws;
  size_t mark_bytes = (((size_t)M * sizeof(int)) + 255) & ~(size_t)255;
  float* subC_A = (float*)((char*)d_ws + mark_bytes);
  float* subH_A = node_buf;

  // 1. copy h_in/c_in into output h/c regions
  long n4 = (long)M * Hc / 4;
  long cb = (n4 + 255) / 256; if (cb > 8192) cb = 8192;
  hipLaunchKernelGGL(copy_hc, dim3((int)cb), dim3(256), 0, stream,
                     (const float4*)h_in, (const float4*)c_in,
                     (float4*)h_out, (float4*)c_out, n4);

  // 2. mark[] : message id -> sub position (or -1)
  hipLaunchKernelGGL(mark_init, dim3((M + 255) / 256), dim3(256), 0, stream, mark, M);
  hipLaunchKernelGGL(mark_set,  dim3((S + 255) / 256), dim3(256), 0, stream, mark, submess, S);

  const int lblocks = (S + TMr - 1) / TMr;
  // 3. depth-0: sub state = 0, write compact buffers
  hipLaunchKernelGGL(lstm_step, dim3(lblocks), dim3(256), 0, stream,
      fmess, submess, bgraph, h_in, c_in, mark,
      (const float*)nullptr, (const float*)nullptr,
      Wi, bi, Wo, bo, Wf, bf, Wu, bu,
      subH_A, subC_A, S, 0);
  // 4. depth-1: read compact buffers, scatter into final h/c
  hipLaunchKernelGGL(lstm_step, dim3(lblocks), dim3(256), 0, stream,
      fmess, submess, bgraph, h_in, c_in, mark,
      subH_A, subC_A,
      Wi, bi, Wo, bo, Wf, bf, Wu, bu,
      h_out, c_out, S, 1);

  // 5. zero node_buf (also erases the sub_h scratch), then node readout
  long nn4 = (long)num_nodes * Hc / 4;
  long zb = (nn4 + 255) / 256; if (zb > 8192) zb = 8192;
  hipLaunchKernelGGL(zero_f4, dim3((int)zb), dim3(256), 0, stream, (float4*)node_buf, nn4);

  const int nblocks = (Nsub + TMr - 1) / TMr;
  hipLaunchKernelGGL(node_readout, dim3(nblocks), dim3(256), 0, stream,
      fnode, agraph, subnode, h_out, Wn, bn, node_buf, S);
}

// Round 2
// 507.602 us; speedup vs baseline: 3.7632x; 3.7632x over previous
//
#include <hip/hip_runtime.h>
#include <cstdint>
#include <cstddef>

#define Hc   128
#define INc  256
#define ZD   (INc + Hc)   // 384
#define Kc   8
#define ZP   392          // z row pad (ushorts): 784B/row -> 16B aligned, 2-way banks
#define HNP  136          // hn row pad: 272B/row -> 16B aligned, 2-way banks
#define ZP2  264          // node z row pad: 528B/row
#define EPD  132          // f32 epilogue arrays pad

typedef unsigned short ushortT;
typedef __attribute__((ext_vector_type(8))) short bf16x8;
typedef __attribute__((ext_vector_type(4))) float f32x4;
typedef __attribute__((ext_vector_type(4))) unsigned short us4;

__device__ __forceinline__ float fsig(float x) {
  x = fminf(fmaxf(x, -30.f), 30.f);
  return 1.f / (1.f + __expf(-x));
}
__device__ __forceinline__ float ftanh(float x) {
  x = fminf(fmaxf(x, -15.f), 15.f);
  float e = __expf(2.f * x);
  return (e - 1.f) / (e + 1.f);
}
__device__ __forceinline__ ushortT f2bf(float f) {
  unsigned u = __builtin_bit_cast(unsigned, f);
  unsigned r = (u + 0x7fffu + ((u >> 16) & 1u)) >> 16;
  return (ushortT)r;
}
__device__ __forceinline__ us4 f2bf4(float4 v) {
  us4 o; o[0] = f2bf(v.x); o[1] = f2bf(v.y); o[2] = f2bf(v.z); o[3] = f2bf(v.w);
  return o;
}

// ---------------- utility kernels ----------------
__global__ void copy_hc(const float4* __restrict__ h_in, const float4* __restrict__ c_in,
                        float4* __restrict__ h_out, float4* __restrict__ c_out, long n4) {
  long i = (long)blockIdx.x * blockDim.x + threadIdx.x;
  long stride = (long)gridDim.x * blockDim.x;
  for (; i < n4; i += stride) { h_out[i] = h_in[i]; c_out[i] = c_in[i]; }
}

__global__ void zero_f4(float4* __restrict__ p, long n4) {
  long i = (long)blockIdx.x * blockDim.x + threadIdx.x;
  long stride = (long)gridDim.x * blockDim.x;
  float4 z; z.x = z.y = z.z = z.w = 0.f;
  for (; i < n4; i += stride) p[i] = z;
}

__global__ void mark_init(int* __restrict__ mark, int M) {
  int i = blockIdx.x * blockDim.x + threadIdx.x;
  if (i < M) mark[i] = -1;
}
__global__ void mark_set(int* __restrict__ mark, const int* __restrict__ submess, int S) {
  int i = blockIdx.x * blockDim.x + threadIdx.x;
  if (i < S) mark[submess[i]] = i;
}

// ---------------- weight repack into B-fragment order ----------------
// gates: frag id  idx = ((g*8 + c)*12 + kt)*64 + lane ; elem j:
//        W_g[kt*32 + (lane>>4)*8 + j][c*16 + (lane&15)]
// Wn:    i2 = ((c*8 + kt)*64 + lane), at pack + 196608
#define GATE_FRAGS (4*8*12*64)
#define WN_FRAGS   (8*8*64)
__global__ void repack_weights(const float* __restrict__ Wi, const float* __restrict__ Wo,
                               const float* __restrict__ Wu, const float* __restrict__ Wf,
                               const float* __restrict__ Wn, ushortT* __restrict__ pack) {
  int idx = blockIdx.x * blockDim.x + threadIdx.x;
  if (idx < GATE_FRAGS) {
    int lane = idx & 63;
    int kt = (idx >> 6) % 12;
    int gc = idx / (64 * 12);
    int c = gc & 7, g = gc >> 3;
    const float* W = (g == 0) ? Wi : (g == 1) ? Wo : (g == 2) ? Wu : Wf;
    int k0 = kt * 32 + (lane >> 4) * 8;
    int col = c * 16 + (lane & 15);
    ushortT* dst = pack + (size_t)idx * 8;
    #pragma unroll
    for (int j = 0; j < 8; ++j) dst[j] = f2bf(W[(size_t)(k0 + j) * Hc + col]);
  } else if (idx < GATE_FRAGS + WN_FRAGS) {
    int i2 = idx - GATE_FRAGS;
    int lane = i2 & 63;
    int kt = (i2 >> 6) & 7;
    int c = i2 >> 9;
    int k0 = kt * 32 + (lane >> 4) * 8;
    int col = c * 16 + (lane & 15);
    ushortT* dst = pack + (size_t)GATE_FRAGS * 8 + (size_t)i2 * 8;
    #pragma unroll
    for (int j = 0; j < 8; ++j) dst[j] = f2bf(Wn[(size_t)(k0 + j) * Hc + col]);
  }
}

// ---------------- LSTM step (MFMA) ----------------
__global__ __launch_bounds__(256) void lstm_step_mfma(
    const float* __restrict__ fmess, const int* __restrict__ submess,
    const int* __restrict__ bgraph, const float* __restrict__ h_in,
    const float* __restrict__ c_in, const int* __restrict__ mark,
    const float* __restrict__ subH_src, const float* __restrict__ subC_src,
    const ushortT* __restrict__ pack,
    const float* __restrict__ bi, const float* __restrict__ bo,
    const float* __restrict__ bu, const float* __restrict__ bfb,
    float* __restrict__ dstH, float* __restrict__ dstC,
    int S, int scatter_dst)
{
  // z (bf16 [16][ZP]) unioned with epilogue f32 arrays cst/osg/fxl [16][EPD]
  __shared__ __align__(16) unsigned char poolc[3 * 16 * EPD * 4];   // 25344B
  __shared__ __align__(16) ushortT hns[128 * HNP];                  // 34816B
  __shared__ int msrow[16];
  __shared__ const float* hptr[16][Kc];
  __shared__ const float* cptr[16][Kc];

  ushortT* zs = (ushortT*)poolc;
  float* cst = (float*)poolc;
  float* osg = cst + 16 * EPD;
  float* fxl = osg + 16 * EPD;

  const int t = threadIdx.x;
  const int row0 = blockIdx.x * 16;

  if (t < 16) msrow[t] = (row0 + t < S) ? submess[row0 + t] : -1;
  __syncthreads();

  // ---- stage x into z[:,0:256]; build neighbor pointer tables ----
  {
    int r = t >> 4, cp = t & 15;
    int ms = msrow[r];
    const float4* xr = (ms >= 0) ? (const float4*)(fmess + (size_t)ms * INc) : nullptr;
    #pragma unroll
    for (int q = 0; q < 4; ++q) {
      int slot = cp + q * 16;
      float4 v;
      if (xr) v = xr[slot]; else { v.x = v.y = v.z = v.w = 0.f; }
      *(us4*)&zs[r * ZP + slot * 4] = f2bf4(v);
    }
  }
  if (t < 128) {
    int r = t >> 3, k = t & 7;
    int ms = msrow[r];
    const float* hp0 = nullptr; const float* cp0 = nullptr;
    if (ms >= 0) {
      int j = bgraph[(size_t)ms * Kc + k];
      int m = mark[j];
      if (m >= 0) {
        if (subH_src) { hp0 = subH_src + (size_t)m * Hc; cp0 = subC_src + (size_t)m * Hc; }
      } else {
        hp0 = h_in + (size_t)j * Hc; cp0 = c_in + (size_t)j * Hc;
      }
    }
    hptr[r][k] = hp0; cptr[r][k] = cp0;
  }
  __syncthreads();

  // ---- gather h_nei -> hns (bf16), sum -> z[:,256:384] ----
  {
    int r = t >> 4, cp = t & 15;
    float4 s0, s1; s0.x = s0.y = s0.z = s0.w = 0.f; s1 = s0;
    #pragma unroll
    for (int k = 0; k < Kc; ++k) {
      const float* hp0 = hptr[r][k];
      float4 v0, v1; v0.x = v0.y = v0.z = v0.w = 0.f; v1 = v0;
      if (hp0) { v0 = ((const float4*)hp0)[cp]; v1 = ((const float4*)hp0)[cp + 16]; }
      s0.x += v0.x; s0.y += v0.y; s0.z += v0.z; s0.w += v0.w;
      s1.x += v1.x; s1.y += v1.y; s1.z += v1.z; s1.w += v1.w;
      *(us4*)&hns[(r * 8 + k) * HNP + cp * 4] = f2bf4(v0);
      *(us4*)&hns[(r * 8 + k) * HNP + 64 + cp * 4] = f2bf4(v1);
    }
    *(us4*)&zs[r * ZP + INc + cp * 4] = f2bf4(s0);
    *(us4*)&zs[r * ZP + INc + 64 + cp * 4] = f2bf4(s1);
  }
  __syncthreads();

  const int w = t >> 6, lane = t & 63;
  const int lg = lane >> 4, cl = lane & 15;

  // ---- gate K-loop: wave w covers cols [32w, 32w+32) of each gate ----
  f32x4 acc[8];
  #pragma unroll
  for (int i = 0; i < 8; ++i) acc[i] = (f32x4){0.f, 0.f, 0.f, 0.f};

  const ushortT* zrow = &zs[cl * ZP + lg * 8];
  #pragma unroll
  for (int kt = 0; kt < 12; ++kt) {
    bf16x8 a = *(const bf16x8*)&zrow[kt * 32];
    #pragma unroll
    for (int tix = 0; tix < 8; ++tix) {
      int g = tix >> 1;
      if (g == 3 && kt >= 8) continue;     // fx uses x-part only
      int cw = w * 2 + (tix & 1);
      bf16x8 b = *(const bf16x8*)&pack[(size_t)(((g * 8 + cw) * 12 + kt) * 64 + lane) * 8];
      acc[tix] = __builtin_amdgcn_mfma_f32_16x16x32_bf16(a, b, acc[tix], 0, 0, 0);
    }
  }
  __syncthreads();   // all A-frag reads of z done; poolc may be overwritten

  // ---- gate epilogue: cstart, sigmoid(o), fx -> LDS f32 ----
  #pragma unroll
  for (int half = 0; half < 2; ++half) {
    int col = (w * 2 + half) * 16 + cl;
    float biv = bi[col], bov = bo[col], buv = bu[col], bfv = bfb[col];
    f32x4 ia = acc[0 + half], oa = acc[2 + half], ua = acc[4 + half], fa = acc[6 + half];
    #pragma unroll
    for (int reg = 0; reg < 4; ++reg) {
      int row = lg * 4 + reg;
      float iv = fsig(ia[reg] + biv);
      float ov = fsig(oa[reg] + bov);
      float uv = ftanh(ua[reg] + buv);
      cst[row * EPD + col] = iv * uv;
      osg[row * EPD + col] = ov;
      fxl[row * EPD + col] = fa[reg] + bfv;
    }
  }
  __syncthreads();

  // ---- f-phase: [128 pairs x 128] @ Wf2, fused c/h epilogue ----
  bf16x8 fbf[2][4];
  #pragma unroll
  for (int half = 0; half < 2; ++half)
    #pragma unroll
    for (int kf = 0; kf < 4; ++kf) {
      int cw = w * 2 + half;
      fbf[half][kf] = *(const bf16x8*)&pack[(size_t)(((3 * 8 + cw) * 12 + (8 + kf)) * 64 + lane) * 8];
    }

  const int rOff = lg >> 1;
  const int kbase = (lg & 1) * 4;
  #pragma unroll
  for (int mt = 0; mt < 8; ++mt) {
    f32x4 fa0 = (f32x4){0.f, 0.f, 0.f, 0.f};
    f32x4 fa1 = (f32x4){0.f, 0.f, 0.f, 0.f};
    const ushortT* hrow = &hns[(mt * 16 + cl) * HNP + lg * 8];
    #pragma unroll
    for (int kf = 0; kf < 4; ++kf) {
      bf16x8 a = *(const bf16x8*)&hrow[kf * 32];
      fa0 = __builtin_amdgcn_mfma_f32_16x16x32_bf16(a, fbf[0][kf], fa0, 0, 0, 0);
      fa1 = __builtin_amdgcn_mfma_f32_16x16x32_bf16(a, fbf[1][kf], fa1, 0, 0, 0);
    }
    int rA = mt * 2 + rOff;
    #pragma unroll
    for (int half = 0; half < 2; ++half) {
      int col = (w * 2 + half) * 16 + cl;
      f32x4 fv = half ? fa1 : fa0;
      float fxv = fxl[rA * EPD + col];
      float partial = 0.f;
      #pragma unroll
      for (int reg = 0; reg < 4; ++reg) {
        int k = kbase + reg;
        float fval = fsig(fv[reg] + fxv);
        const float* cp0 = cptr[rA][k];
        float cv = cp0 ? cp0[col] : 0.f;
        partial = fmaf(fval, cv, partial);
      }
      float tot = partial + __shfl_xor(partial, 16);
      if ((lg & 1) == 0) {
        int ms = msrow[rA];
        if (ms >= 0) {
          float cfin = tot + cst[rA * EPD + col];
          float hfin = osg[rA * EPD + col] * ftanh(cfin);
          size_t orow = scatter_dst ? (size_t)ms : (size_t)(row0 + rA);
          dstH[orow * Hc + col] = hfin;
          dstC[orow * Hc + col] = cfin;
        }
      }
    }
  }
}

// ---------------- node readout (MFMA) ----------------
__global__ __launch_bounds__(256) void node_readout_mfma(
    const float* __restrict__ fnode, const int* __restrict__ agraph,
    const int* __restrict__ subnode, const float* __restrict__ hfull,
    const ushortT* __restrict__ packWn, const float* __restrict__ bn,
    float* __restrict__ node_buf, int Nsub)
{
  __shared__ __align__(16) ushortT z2[16 * ZP2];   // 8448B
  __shared__ int orow[16];
  __shared__ const float* aptr[16][Kc];

  const int t = threadIdx.x;
  const int row0 = blockIdx.x * 16;

  if (t < 16) orow[t] = (row0 + t < Nsub) ? subnode[row0 + t] : -1;
  if (t >= 64 && t < 64 + 128) {
    int i = t - 64, r = i >> 3, k = i & 7;
    int v = row0 + r;
    aptr[r][k] = (v < Nsub) ? hfull + (size_t)agraph[(size_t)v * Kc + k] * Hc : nullptr;
  }
  {
    int r = t >> 4, cp = t & 15;
    int v = row0 + r;
    const float4* fr = (v < Nsub) ? (const float4*)(fnode + (size_t)v * Hc) : nullptr;
    float4 v0, v1; v0.x = v0.y = v0.z = v0.w = 0.f; v1 = v0;
    if (fr) { v0 = fr[cp]; v1 = fr[cp + 16]; }
    *(us4*)&z2[r * ZP2 + cp * 4] = f2bf4(v0);
    *(us4*)&z2[r * ZP2 + 64 + cp * 4] = f2bf4(v1);
  }
  __syncthreads();
  {
    int r = t >> 4, cp = t & 15;
    float4 s0, s1; s0.x = s0.y = s0.z = s0.w = 0.f; s1 = s0;
    #pragma unroll
    for (int k = 0; k < Kc; ++k) {
      const float* p = aptr[r][k];
      if (p) {
        float4 v0 = ((const float4*)p)[cp], v1 = ((const float4*)p)[cp + 16];
        s0.x += v0.x; s0.y += v0.y; s0.z += v0.z; s0.w += v0.w;
        s1.x += v1.x; s1.y += v1.y; s1.z += v1.z; s1.w += v1.w;
      }
    }
    *(us4*)&z2[r * ZP2 + Hc + cp * 4] = f2bf4(s0);
    *(us4*)&z2[r * ZP2 + Hc + 64 + cp * 4] = f2bf4(s1);
  }
  __syncthreads();

  const int w = t >> 6, lane = t & 63;
  const int lg = lane >> 4, cl = lane & 15;

  f32x4 acc0 = (f32x4){0.f, 0.f, 0.f, 0.f};
  f32x4 acc1 = (f32x4){0.f, 0.f, 0.f, 0.f};
  const ushortT* zr = &z2[cl * ZP2 + lg * 8];
  #pragma unroll
  for (int kt = 0; kt < 8; ++kt) {
    bf16x8 a = *(const bf16x8*)&zr[kt * 32];
    bf16x8 b0 = *(const bf16x8*)&packWn[(size_t)(((w * 2 + 0) * 8 + kt) * 64 + lane) * 8];
    bf16x8 b1 = *(const bf16x8*)&packWn[(size_t)(((w * 2 + 1) * 8 + kt) * 64 + lane) * 8];
    acc0 = __builtin_amdgcn_mfma_f32_16x16x32_bf16(a, b0, acc0, 0, 0, 0);
    acc1 = __builtin_amdgcn_mfma_f32_16x16x32_bf16(a, b1, acc1, 0, 0, 0);
  }
  #pragma unroll
  for (int half = 0; half < 2; ++half) {
    int col = (w * 2 + half) * 16 + cl;
    float bnv = bn[col];
    f32x4 a_ = half ? acc1 : acc0;
    #pragma unroll
    for (int reg = 0; reg < 4; ++reg) {
      int row = lg * 4 + reg;
      int o = orow[row];
      if (o >= 0) node_buf[(size_t)o * Hc + col] = fmaxf(a_[reg] + bnv, 0.f);
    }
  }
}

// ---------------- launch ----------------
extern "C" void kernel_launch(void* const* d_in, const int* in_sizes, int n_in,
                              void* d_out, int out_size, void* d_ws, size_t ws_size,
                              hipStream_t stream) {
  const float* fnode   = (const float*)d_in[0];
  const float* fmess   = (const float*)d_in[1];
  const int*   agraph  = (const int*)d_in[2];
  const int*   bgraph  = (const int*)d_in[3];
  const float* h_in    = (const float*)d_in[4];
  const float* c_in    = (const float*)d_in[5];
  const int*   submess = (const int*)d_in[6];
  const int*   subnode = (const int*)d_in[7];
  const float* Wi = (const float*)d_in[9];
  const float* bi = (const float*)d_in[10];
  const float* Wo = (const float*)d_in[11];
  const float* bo = (const float*)d_in[12];
  const float* Wf = (const float*)d_in[13];
  const float* bf_ = (const float*)d_in[14];
  const float* Wu = (const float*)d_in[15];
  const float* bu = (const float*)d_in[16];
  const float* Wn = (const float*)d_in[17];
  const float* bn = (const float*)d_in[18];

  const int S    = in_sizes[6];
  const int Nsub = in_sizes[2] / Kc;
  const int M    = in_sizes[4] / Hc;
  const int num_nodes = out_size / Hc - 2 * M;

  float* node_buf = (float*)d_out;
  float* h_out = node_buf + (size_t)num_nodes * Hc;
  float* c_out = h_out + (size_t)M * Hc;

  // workspace: mark[M] | pack (gates+Wn bf16) | compact sub_c
  int* mark = (int*)d_ws;
  size_t mark_bytes = (((size_t)M * sizeof(int)) + 255) & ~(size_t)255;
  ushortT* pack = (ushortT*)((char*)d_ws + mark_bytes);
  size_t pack_bytes = (((size_t)(GATE_FRAGS + WN_FRAGS) * 8 * sizeof(ushortT)) + 255) & ~(size_t)255;
  float* subC_A = (float*)((char*)d_ws + mark_bytes + pack_bytes);
  float* subH_A = node_buf;   // compact sub_h scratch in node_buf region
  ushortT* packWn = pack + (size_t)GATE_FRAGS * 8;

  // 1. h/c passthrough copy
  long n4 = (long)M * Hc / 4;
  long cb = (n4 + 255) / 256; if (cb > 8192) cb = 8192;
  hipLaunchKernelGGL(copy_hc, dim3((int)cb), dim3(256), 0, stream,
                     (const float4*)h_in, (const float4*)c_in,
                     (float4*)h_out, (float4*)c_out, n4);

  // 2. mark + weight repack
  hipLaunchKernelGGL(mark_init, dim3((M + 255) / 256), dim3(256), 0, stream, mark, M);
  hipLaunchKernelGGL(mark_set,  dim3((S + 255) / 256), dim3(256), 0, stream, mark, submess, S);
  hipLaunchKernelGGL(repack_weights, dim3((GATE_FRAGS + WN_FRAGS + 255) / 256), dim3(256), 0, stream,
                     Wi, Wo, Wu, Wf, Wn, pack);

  const int lblocks = (S + 15) / 16;
  // 3. depth-0 (sub state = 0) -> compact
  hipLaunchKernelGGL(lstm_step_mfma, dim3(lblocks), dim3(256), 0, stream,
      fmess, submess, bgraph, h_in, c_in, mark,
      (const float*)nullptr, (const float*)nullptr, pack,
      bi, bo, bu, bf_, subH_A, subC_A, S, 0);
  // 4. depth-1 -> scatter into final h/c
  hipLaunchKernelGGL(lstm_step_mfma, dim3(lblocks), dim3(256), 0, stream,
      fmess, submess, bgraph, h_in, c_in, mark,
      subH_A, subC_A, pack,
      bi, bo, bu, bf_, h_out, c_out, S, 1);

  // 5. zero node_buf (erases sub_h scratch), node readout
  long nn4 = (long)num_nodes * Hc / 4;
  long zb = (nn4 + 255) / 256; if (zb > 8192) zb = 8192;
  hipLaunchKernelGGL(zero_f4, dim3((int)zb), dim3(256), 0, stream, (float4*)node_buf, nn4);

  const int nblocks = (Nsub + 15) / 16;
  hipLaunchKernelGGL(node_readout_mfma, dim3(nblocks), dim3(256), 0, stream,
      fnode, agraph, subnode, h_out, packWn, bn, node_buf, S);
}

// Round 3
// 415.941 us; speedup vs baseline: 4.5925x; 1.2204x over previous
//
#include <hip/hip_runtime.h>
#include <cstdint>
#include <cstddef>

#define Hc   128
#define INc  256
#define ZD   (INc + Hc)   // 384
#define Kc   8
#define ZP   392          // z row pad (ushorts): 784B/row
#define HP   136          // precompute/update staging row pad (ushorts)
#define ZP2  264          // node z row pad

typedef unsigned short ushortT;
typedef __attribute__((ext_vector_type(8))) short bf16x8;
typedef __attribute__((ext_vector_type(4))) float f32x4;
typedef __attribute__((ext_vector_type(4))) unsigned short us4;
typedef __attribute__((ext_vector_type(8))) unsigned short us8;

__device__ __forceinline__ float fsig(float x) {
  x = fminf(fmaxf(x, -30.f), 30.f);
  return 1.f / (1.f + __expf(-x));
}
__device__ __forceinline__ float ftanh(float x) {
  x = fminf(fmaxf(x, -15.f), 15.f);
  float e = __expf(2.f * x);
  return (e - 1.f) / (e + 1.f);
}
__device__ __forceinline__ ushortT f2bf(float f) {
  unsigned u = __builtin_bit_cast(unsigned, f);
  unsigned r = (u + 0x7fffu + ((u >> 16) & 1u)) >> 16;
  return (ushortT)r;
}
__device__ __forceinline__ us4 f2bf4(float4 v) {
  us4 o; o[0] = f2bf(v.x); o[1] = f2bf(v.y); o[2] = f2bf(v.z); o[3] = f2bf(v.w);
  return o;
}
__device__ __forceinline__ float bf2f(ushortT u) {
  return __builtin_bit_cast(float, (unsigned)u << 16);
}

// ---------------- utility kernels ----------------
__global__ void zero_f4(float4* __restrict__ p, long n4) {
  long i = (long)blockIdx.x * blockDim.x + threadIdx.x;
  long stride = (long)gridDim.x * blockDim.x;
  float4 z; z.x = z.y = z.z = z.w = 0.f;
  for (; i < n4; i += stride) p[i] = z;
}
__global__ void mark_init(int* __restrict__ mark, int M) {
  int i = blockIdx.x * blockDim.x + threadIdx.x;
  if (i < M) mark[i] = -1;
}
__global__ void mark_set(int* __restrict__ mark, const int* __restrict__ submess, int S) {
  int i = blockIdx.x * blockDim.x + threadIdx.x;
  if (i < S) mark[submess[i]] = i;
}

// ---------------- weight repack into B-fragment order (unchanged, verified R2) ----
#define GATE_FRAGS (4*8*12*64)
#define WN_FRAGS   (8*8*64)
__global__ void repack_weights(const float* __restrict__ Wi, const float* __restrict__ Wo,
                               const float* __restrict__ Wu, const float* __restrict__ Wf,
                               const float* __restrict__ Wn, ushortT* __restrict__ pack) {
  int idx = blockIdx.x * blockDim.x + threadIdx.x;
  if (idx < GATE_FRAGS) {
    int lane = idx & 63;
    int kt = (idx >> 6) % 12;
    int gc = idx / (64 * 12);
    int c = gc & 7, g = gc >> 3;
    const float* W = (g == 0) ? Wi : (g == 1) ? Wo : (g == 2) ? Wu : Wf;
    int k0 = kt * 32 + (lane >> 4) * 8;
    int col = c * 16 + (lane & 15);
    ushortT* dst = pack + (size_t)idx * 8;
    #pragma unroll
    for (int j = 0; j < 8; ++j) dst[j] = f2bf(W[(size_t)(k0 + j) * Hc + col]);
  } else if (idx < GATE_FRAGS + WN_FRAGS) {
    int i2 = idx - GATE_FRAGS;
    int lane = i2 & 63;
    int kt = (i2 >> 6) & 7;
    int c = i2 >> 9;
    int k0 = kt * 32 + (lane >> 4) * 8;
    int col = c * 16 + (lane & 15);
    ushortT* dst = pack + (size_t)GATE_FRAGS * 8 + (size_t)i2 * 8;
    #pragma unroll
    for (int j = 0; j < 8; ++j) dst[j] = f2bf(Wn[(size_t)(k0 + j) * Hc + col]);
  }
}

// Wf2 B-fragment (reuses gate pack, g=3, kt=8..11 == Wf rows 256..383)
__device__ __forceinline__ const bf16x8* wf2_frag(const ushortT* pack, int cw, int kf, int lane) {
  return (const bf16x8*)&pack[(size_t)(((3 * 8 + cw) * 12 + (8 + kf)) * 64 + lane) * 8];
}

// ---------------- precompute: passthrough + masked bf16 shadows + Hf = h@Wf2 ----
__global__ __launch_bounds__(256) void precompute(
    const float* __restrict__ h_in, const float* __restrict__ c_in,
    const int* __restrict__ mark, const ushortT* __restrict__ pack,
    float* __restrict__ h_out, float* __restrict__ c_out,
    ushortT* __restrict__ H16, ushortT* __restrict__ C16, ushortT* __restrict__ Hf16,
    int M)
{
  __shared__ __align__(16) ushortT zh[16 * HP];
  __shared__ int mskL[16];
  const int t = threadIdx.x;
  const int row0 = blockIdx.x * 16;

  if (t < 16) mskL[t] = (row0 + t < M) ? (mark[row0 + t] >= 0 ? 1 : 0) : 1;
  __syncthreads();
  {
    int r = t >> 4, cp = t & 15;
    int j = row0 + r;
    bool ok = (j < M);
    int msk = mskL[r];
    float4 a0, a1, b0, b1;
    a0.x=a0.y=a0.z=a0.w=0.f; a1=a0; b0=a0; b1=a0;
    if (ok) {
      const float4* h4 = (const float4*)(h_in + (size_t)j * Hc);
      const float4* c4 = (const float4*)(c_in + (size_t)j * Hc);
      a0 = h4[cp]; a1 = h4[cp + 16]; b0 = c4[cp]; b1 = c4[cp + 16];
      // f32 passthrough (unmasked)
      ((float4*)(h_out + (size_t)j * Hc))[cp] = a0;
      ((float4*)(h_out + (size_t)j * Hc))[cp + 16] = a1;
      ((float4*)(c_out + (size_t)j * Hc))[cp] = b0;
      ((float4*)(c_out + (size_t)j * Hc))[cp + 16] = b1;
    }
    us4 zz; zz[0]=zz[1]=zz[2]=zz[3]=0;
    us4 ha0 = msk ? zz : f2bf4(a0), ha1 = msk ? zz : f2bf4(a1);
    us4 ca0 = msk ? zz : f2bf4(b0), ca1 = msk ? zz : f2bf4(b1);
    if (ok) {
      *(us4*)&H16[(size_t)j * Hc + cp * 4] = ha0;
      *(us4*)&H16[(size_t)j * Hc + 64 + cp * 4] = ha1;
      *(us4*)&C16[(size_t)j * Hc + cp * 4] = ca0;
      *(us4*)&C16[(size_t)j * Hc + 64 + cp * 4] = ca1;
    }
    *(us4*)&zh[r * HP + cp * 4] = ha0;
    *(us4*)&zh[r * HP + 64 + cp * 4] = ha1;
  }
  __syncthreads();

  const int w = t >> 6, lane = t & 63, lg = lane >> 4, cl = lane & 15;
  f32x4 acc0 = (f32x4){0.f,0.f,0.f,0.f}, acc1 = acc0;
  const ushortT* zr = &zh[cl * HP + lg * 8];
  #pragma unroll
  for (int kf = 0; kf < 4; ++kf) {
    bf16x8 a = *(const bf16x8*)&zr[kf * 32];
    acc0 = __builtin_amdgcn_mfma_f32_16x16x32_bf16(a, *wf2_frag(pack, w*2+0, kf, lane), acc0, 0, 0, 0);
    acc1 = __builtin_amdgcn_mfma_f32_16x16x32_bf16(a, *wf2_frag(pack, w*2+1, kf, lane), acc1, 0, 0, 0);
  }
  #pragma unroll
  for (int half = 0; half < 2; ++half) {
    int col = (w * 2 + half) * 16 + cl;
    f32x4 a_ = half ? acc1 : acc0;
    #pragma unroll
    for (int reg = 0; reg < 4; ++reg) {
      int j = row0 + lg * 4 + reg;
      if (j < M) Hf16[(size_t)j * Hc + col] = f2bf(a_[reg]);
    }
  }
}

// ---------------- update shadows at sub rows from iter-0 output ----------------
__global__ __launch_bounds__(256) void update_sub(
    const float* __restrict__ h_out, const float* __restrict__ c_out,
    const int* __restrict__ submess, const ushortT* __restrict__ pack,
    ushortT* __restrict__ H16, ushortT* __restrict__ C16, ushortT* __restrict__ Hf16,
    int S)
{
  __shared__ __align__(16) ushortT zh[16 * HP];
  __shared__ int msL[16];
  const int t = threadIdx.x;
  const int row0 = blockIdx.x * 16;

  if (t < 16) msL[t] = (row0 + t < S) ? submess[row0 + t] : -1;
  __syncthreads();
  {
    int r = t >> 4, cp = t & 15;
    int ms = msL[r];
    float4 a0, a1, b0, b1;
    a0.x=a0.y=a0.z=a0.w=0.f; a1=a0; b0=a0; b1=a0;
    if (ms >= 0) {
      const float4* h4 = (const float4*)(h_out + (size_t)ms * Hc);
      const float4* c4 = (const float4*)(c_out + (size_t)ms * Hc);
      a0 = h4[cp]; a1 = h4[cp + 16]; b0 = c4[cp]; b1 = c4[cp + 16];
    }
    us4 ha0 = f2bf4(a0), ha1 = f2bf4(a1);
    if (ms >= 0) {
      *(us4*)&H16[(size_t)ms * Hc + cp * 4] = ha0;
      *(us4*)&H16[(size_t)ms * Hc + 64 + cp * 4] = ha1;
      *(us4*)&C16[(size_t)ms * Hc + cp * 4] = f2bf4(b0);
      *(us4*)&C16[(size_t)ms * Hc + 64 + cp * 4] = f2bf4(b1);
    }
    *(us4*)&zh[r * HP + cp * 4] = ha0;
    *(us4*)&zh[r * HP + 64 + cp * 4] = ha1;
  }
  __syncthreads();

  const int w = t >> 6, lane = t & 63, lg = lane >> 4, cl = lane & 15;
  f32x4 acc0 = (f32x4){0.f,0.f,0.f,0.f}, acc1 = acc0;
  const ushortT* zr = &zh[cl * HP + lg * 8];
  #pragma unroll
  for (int kf = 0; kf < 4; ++kf) {
    bf16x8 a = *(const bf16x8*)&zr[kf * 32];
    acc0 = __builtin_amdgcn_mfma_f32_16x16x32_bf16(a, *wf2_frag(pack, w*2+0, kf, lane), acc0, 0, 0, 0);
    acc1 = __builtin_amdgcn_mfma_f32_16x16x32_bf16(a, *wf2_frag(pack, w*2+1, kf, lane), acc1, 0, 0, 0);
  }
  #pragma unroll
  for (int half = 0; half < 2; ++half) {
    int col = (w * 2 + half) * 16 + cl;
    f32x4 a_ = half ? acc1 : acc0;
    #pragma unroll
    for (int reg = 0; reg < 4; ++reg) {
      int ms = msL[lg * 4 + reg];
      if (ms >= 0) Hf16[(size_t)ms * Hc + col] = f2bf(a_[reg]);
    }
  }
}

// ---------------- LSTM step: gate MFMAs + gather-based f-gate epilogue --------
__global__ __launch_bounds__(256) void lstm_step2(
    const float* __restrict__ fmess, const int* __restrict__ submess,
    const int* __restrict__ bgraph,
    const ushortT* __restrict__ H16, const ushortT* __restrict__ C16,
    const ushortT* __restrict__ Hf16,
    const ushortT* __restrict__ pack,
    const float* __restrict__ bi, const float* __restrict__ bo,
    const float* __restrict__ bu, const float* __restrict__ bfb,
    float* __restrict__ dstH, float* __restrict__ dstC, int S)
{
  __shared__ __align__(16) ushortT zs[16 * ZP];   // 12544B
  __shared__ int nbj[16][Kc];
  __shared__ int msrow[16];

  const int t = threadIdx.x;
  const int row0 = blockIdx.x * 16;

  if (t < 16) msrow[t] = (row0 + t < S) ? submess[row0 + t] : -1;
  __syncthreads();

  // stage x (bf16) + neighbor ids
  {
    int r = t >> 4, cp = t & 15;
    int ms = msrow[r];
    const float4* xr = (ms >= 0) ? (const float4*)(fmess + (size_t)ms * INc) : nullptr;
    #pragma unroll
    for (int q = 0; q < 4; ++q) {
      int slot = cp + q * 16;
      float4 v;
      if (xr) v = xr[slot]; else { v.x = v.y = v.z = v.w = 0.f; }
      *(us4*)&zs[r * ZP + slot * 4] = f2bf4(v);
    }
  }
  if (t < 128) {
    int r = t >> 3, k = t & 7;
    int ms = msrow[r];
    nbj[r][k] = (ms >= 0) ? bgraph[(size_t)ms * Kc + k] : 0;
  }
  __syncthreads();

  // h_sum from bf16 shadow (uniform, branch-free)
  {
    int r = t >> 4, cp = t & 15;
    float sum[8] = {0.f,0.f,0.f,0.f,0.f,0.f,0.f,0.f};
    #pragma unroll
    for (int k = 0; k < Kc; ++k) {
      int j = nbj[r][k];
      us8 v = *(const us8*)&H16[(size_t)j * Hc + cp * 8];
      #pragma unroll
      for (int e = 0; e < 8; ++e) sum[e] += bf2f(v[e]);
    }
    us4 o0, o1;
    #pragma unroll
    for (int e = 0; e < 4; ++e) { o0[e] = f2bf(sum[e]); o1[e] = f2bf(sum[4 + e]); }
    *(us4*)&zs[r * ZP + INc + cp * 8] = o0;
    *(us4*)&zs[r * ZP + INc + cp * 8 + 4] = o1;
  }
  __syncthreads();

  const int w = t >> 6, lane = t & 63, lg = lane >> 4, cl = lane & 15;

  // gate K-loop: 88 MFMAs/wave (i,o,u over 12 kt; fx over 8 kt), 2 col-tiles each
  f32x4 acc[8];
  #pragma unroll
  for (int i = 0; i < 8; ++i) acc[i] = (f32x4){0.f, 0.f, 0.f, 0.f};

  const ushortT* zrow = &zs[cl * ZP + lg * 8];
  const ushortT* bp = pack + (size_t)lane * 8;
  #pragma unroll
  for (int kt = 0; kt < 12; ++kt) {
    bf16x8 a = *(const bf16x8*)&zrow[kt * 32];
    #pragma unroll
    for (int tix = 0; tix < 8; ++tix) {
      int g = tix >> 1;
      if (g == 3 && kt >= 8) continue;
      int cw = w * 2 + (tix & 1);
      bf16x8 b = *(const bf16x8*)(bp + ((size_t)((g * 8 + cw) * 12 + kt)) * 512);
      acc[tix] = __builtin_amdgcn_mfma_f32_16x16x32_bf16(a, b, acc[tix], 0, 0, 0);
    }
  }

  // epilogue: all in registers + branch-free bf16 gathers of Hf/C shadows
  #pragma unroll
  for (int half = 0; half < 2; ++half) {
    int col = (w * 2 + half) * 16 + cl;
    float biv = bi[col], bov = bo[col], buv = bu[col], bfv = bfb[col];
    f32x4 ia = acc[0 + half], oa = acc[2 + half], ua = acc[4 + half], fa = acc[6 + half];
    #pragma unroll
    for (int reg = 0; reg < 4; ++reg) {
      int rA = lg * 4 + reg;
      float iv = fsig(ia[reg] + biv);
      float ov = fsig(oa[reg] + bov);
      float uv = ftanh(ua[reg] + buv);
      float fx = fa[reg] + bfv;
      float cacc = iv * uv;
      #pragma unroll
      for (int k = 0; k < Kc; ++k) {
        int j = nbj[rA][k];
        float hf = bf2f(Hf16[(size_t)j * Hc + col]);
        float cv = bf2f(C16[(size_t)j * Hc + col]);
        cacc = fmaf(fsig(fx + hf), cv, cacc);
      }
      int ms = msrow[rA];
      if (ms >= 0) {
        dstH[(size_t)ms * Hc + col] = ov * ftanh(cacc);
        dstC[(size_t)ms * Hc + col] = cacc;
      }
    }
  }
}

// ---------------- node readout (MFMA, unchanged from R2) ----------------
__global__ __launch_bounds__(256) void node_readout_mfma(
    const float* __restrict__ fnode, const int* __restrict__ agraph,
    const int* __restrict__ subnode, const float* __restrict__ hfull,
    const ushortT* __restrict__ packWn, const float* __restrict__ bn,
    float* __restrict__ node_buf, int Nsub)
{
  __shared__ __align__(16) ushortT z2[16 * ZP2];
  __shared__ int orow[16];
  __shared__ const float* aptr[16][Kc];

  const int t = threadIdx.x;
  const int row0 = blockIdx.x * 16;

  if (t < 16) orow[t] = (row0 + t < Nsub) ? subnode[row0 + t] : -1;
  if (t >= 64 && t < 64 + 128) {
    int i = t - 64, r = i >> 3, k = i & 7;
    int v = row0 + r;
    aptr[r][k] = (v < Nsub) ? hfull + (size_t)agraph[(size_t)v * Kc + k] * Hc : nullptr;
  }
  {
    int r = t >> 4, cp = t & 15;
    int v = row0 + r;
    const float4* fr = (v < Nsub) ? (const float4*)(fnode + (size_t)v * Hc) : nullptr;
    float4 v0, v1; v0.x = v0.y = v0.z = v0.w = 0.f; v1 = v0;
    if (fr) { v0 = fr[cp]; v1 = fr[cp + 16]; }
    *(us4*)&z2[r * ZP2 + cp * 4] = f2bf4(v0);
    *(us4*)&z2[r * ZP2 + 64 + cp * 4] = f2bf4(v1);
  }
  __syncthreads();
  {
    int r = t >> 4, cp = t & 15;
    float4 s0, s1; s0.x = s0.y = s0.z = s0.w = 0.f; s1 = s0;
    #pragma unroll
    for (int k = 0; k < Kc; ++k) {
      const float* p = aptr[r][k];
      if (p) {
        float4 v0 = ((const float4*)p)[cp], v1 = ((const float4*)p)[cp + 16];
        s0.x += v0.x; s0.y += v0.y; s0.z += v0.z; s0.w += v0.w;
        s1.x += v1.x; s1.y += v1.y; s1.z += v1.z; s1.w += v1.w;
      }
    }
    *(us4*)&z2[r * ZP2 + Hc + cp * 4] = f2bf4(s0);
    *(us4*)&z2[r * ZP2 + Hc + 64 + cp * 4] = f2bf4(s1);
  }
  __syncthreads();

  const int w = t >> 6, lane = t & 63;
  const int lg = lane >> 4, cl = lane & 15;

  f32x4 acc0 = (f32x4){0.f,0.f,0.f,0.f};
  f32x4 acc1 = (f32x4){0.f,0.f,0.f,0.f};
  const ushortT* zr = &z2[cl * ZP2 + lg * 8];
  #pragma unroll
  for (int kt = 0; kt < 8; ++kt) {
    bf16x8 a = *(const bf16x8*)&zr[kt * 32];
    bf16x8 b0 = *(const bf16x8*)&packWn[(size_t)(((w * 2 + 0) * 8 + kt) * 64 + lane) * 8];
    bf16x8 b1 = *(const bf16x8*)&packWn[(size_t)(((w * 2 + 1) * 8 + kt) * 64 + lane) * 8];
    acc0 = __builtin_amdgcn_mfma_f32_16x16x32_bf16(a, b0, acc0, 0, 0, 0);
    acc1 = __builtin_amdgcn_mfma_f32_16x16x32_bf16(a, b1, acc1, 0, 0, 0);
  }
  #pragma unroll
  for (int half = 0; half < 2; ++half) {
    int col = (w * 2 + half) * 16 + cl;
    float bnv = bn[col];
    f32x4 a_ = half ? acc1 : acc0;
    #pragma unroll
    for (int reg = 0; reg < 4; ++reg) {
      int row = lg * 4 + reg;
      int o = orow[row];
      if (o >= 0) node_buf[(size_t)o * Hc + col] = fmaxf(a_[reg] + bnv, 0.f);
    }
  }
}

// ---------------- launch ----------------
extern "C" void kernel_launch(void* const* d_in, const int* in_sizes, int n_in,
                              void* d_out, int out_size, void* d_ws, size_t ws_size,
                              hipStream_t stream) {
  const float* fnode   = (const float*)d_in[0];
  const float* fmess   = (const float*)d_in[1];
  const int*   agraph  = (const int*)d_in[2];
  const int*   bgraph  = (const int*)d_in[3];
  const float* h_in    = (const float*)d_in[4];
  const float* c_in    = (const float*)d_in[5];
  const int*   submess = (const int*)d_in[6];
  const int*   subnode = (const int*)d_in[7];
  const float* Wi = (const float*)d_in[9];
  const float* bi = (const float*)d_in[10];
  const float* Wo = (const float*)d_in[11];
  const float* bo = (const float*)d_in[12];
  const float* Wf = (const float*)d_in[13];
  const float* bf_ = (const float*)d_in[14];
  const float* Wu = (const float*)d_in[15];
  const float* bu = (const float*)d_in[16];
  const float* Wn = (const float*)d_in[17];
  const float* bn = (const float*)d_in[18];

  const int S    = in_sizes[6];
  const int Nsub = in_sizes[2] / Kc;
  const int M    = in_sizes[4] / Hc;
  const int num_nodes = out_size / Hc - 2 * M;

  float* node_buf = (float*)d_out;
  float* h_out = node_buf + (size_t)num_nodes * Hc;
  float* c_out = h_out + (size_t)M * Hc;

  // ws layout: mark[M] | pack | Hf16[M*128] bf16 | C16[M*128] bf16
  // H16[M*128] bf16 lives in the node_buf region (zeroed only after iter1).
  int* mark = (int*)d_ws;
  size_t off = (((size_t)M * sizeof(int)) + 255) & ~(size_t)255;
  ushortT* pack = (ushortT*)((char*)d_ws + off);
  off += (((size_t)(GATE_FRAGS + WN_FRAGS) * 8 * sizeof(ushortT)) + 255) & ~(size_t)255;
  ushortT* Hf16 = (ushortT*)((char*)d_ws + off);
  off += (((size_t)M * Hc * sizeof(ushortT)) + 255) & ~(size_t)255;
  ushortT* C16 = (ushortT*)((char*)d_ws + off);
  ushortT* H16 = (ushortT*)node_buf;   // 30.7MB <= num_nodes*Hc*4 = 33.5MB
  ushortT* packWn = pack + (size_t)GATE_FRAGS * 8;

  // 1. mark + weight repack
  hipLaunchKernelGGL(mark_init, dim3((M + 255) / 256), dim3(256), 0, stream, mark, M);
  hipLaunchKernelGGL(mark_set,  dim3((S + 255) / 256), dim3(256), 0, stream, mark, submess, S);
  hipLaunchKernelGGL(repack_weights, dim3((GATE_FRAGS + WN_FRAGS + 255) / 256), dim3(256), 0, stream,
                     Wi, Wo, Wu, Wf, Wn, pack);

  // 2. precompute: h/c passthrough + masked bf16 shadows + Hf = masked h @ Wf2
  hipLaunchKernelGGL(precompute, dim3((M + 15) / 16), dim3(256), 0, stream,
                     h_in, c_in, mark, pack, h_out, c_out, H16, C16, Hf16, M);

  const int lblocks = (S + 15) / 16;
  // 3. iter 0: reads shadows, scatters sub_h/sub_c into h_out/c_out
  hipLaunchKernelGGL(lstm_step2, dim3(lblocks), dim3(256), 0, stream,
      fmess, submess, bgraph, H16, C16, Hf16, pack,
      bi, bo, bu, bf_, h_out, c_out, S);
  // 4. refresh shadows at sub rows from iter-0 output
  hipLaunchKernelGGL(update_sub, dim3(lblocks), dim3(256), 0, stream,
      h_out, c_out, submess, pack, H16, C16, Hf16, S);
  // 5. iter 1: identical call; overwrites sub rows of h_out/c_out with final values
  hipLaunchKernelGGL(lstm_step2, dim3(lblocks), dim3(256), 0, stream,
      fmess, submess, bgraph, H16, C16, Hf16, pack,
      bi, bo, bu, bf_, h_out, c_out, S);

  // 6. zero node_buf (erases H16 shadow), then node readout
  long nn4 = (long)num_nodes * Hc / 4;
  long zb = (nn4 + 255) / 256; if (zb > 8192) zb = 8192;
  hipLaunchKernelGGL(zero_f4, dim3((int)zb), dim3(256), 0, stream, (float4*)node_buf, nn4);

  const int nblocks = (Nsub + 15) / 16;
  hipLaunchKernelGGL(node_readout_mfma, dim3(nblocks), dim3(256), 0, stream,
      fnode, agraph, subnode, h_out, packWn, bn, node_buf, S);
}

// Round 4
// 386.392 us; speedup vs baseline: 4.9437x; 1.0765x over previous
//
#include <hip/hip_runtime.h>
#include <cstdint>
#include <cstddef>

#define Hc   128
#define INc  256
#define ZD   (INc + Hc)   // 384
#define Kc   8
#define ZP   392          // z row pad (ushorts): 784B/row
#define HP   136          // precompute/update staging row pad (ushorts)
#define ZP2  264          // node z row pad
#define EPD  132          // f32 epilogue arrays pad (dwords/row)

typedef unsigned short ushortT;
typedef __attribute__((ext_vector_type(8))) short bf16x8;
typedef __attribute__((ext_vector_type(4))) float f32x4;
typedef __attribute__((ext_vector_type(4))) unsigned short us4;
typedef __attribute__((ext_vector_type(8))) unsigned short us8;

__device__ __forceinline__ float fsig(float x) {
  x = fminf(fmaxf(x, -30.f), 30.f);
  return 1.f / (1.f + __expf(-x));
}
__device__ __forceinline__ float ftanh(float x) {
  x = fminf(fmaxf(x, -15.f), 15.f);
  float e = __expf(2.f * x);
  return (e - 1.f) / (e + 1.f);
}
__device__ __forceinline__ ushortT f2bf(float f) {
  unsigned u = __builtin_bit_cast(unsigned, f);
  unsigned r = (u + 0x7fffu + ((u >> 16) & 1u)) >> 16;
  return (ushortT)r;
}
__device__ __forceinline__ us4 f2bf4(float4 v) {
  us4 o; o[0] = f2bf(v.x); o[1] = f2bf(v.y); o[2] = f2bf(v.z); o[3] = f2bf(v.w);
  return o;
}
__device__ __forceinline__ float bf2f(ushortT u) {
  return __builtin_bit_cast(float, (unsigned)u << 16);
}

// ---------------- utility kernels ----------------
__global__ void zero_f4(float4* __restrict__ p, long n4) {
  long i = (long)blockIdx.x * blockDim.x + threadIdx.x;
  long stride = (long)gridDim.x * blockDim.x;
  float4 z; z.x = z.y = z.z = z.w = 0.f;
  for (; i < n4; i += stride) p[i] = z;
}
__global__ void mark_init(int* __restrict__ mark, int M) {
  int i = blockIdx.x * blockDim.x + threadIdx.x;
  if (i < M) mark[i] = -1;
}
__global__ void mark_set(int* __restrict__ mark, const int* __restrict__ submess, int S) {
  int i = blockIdx.x * blockDim.x + threadIdx.x;
  if (i < S) mark[submess[i]] = i;
}

// ---------------- weight repack into B-fragment order (verified R2/R3) ----------
#define GATE_FRAGS (4*8*12*64)
#define WN_FRAGS   (8*8*64)
__global__ void repack_weights(const float* __restrict__ Wi, const float* __restrict__ Wo,
                               const float* __restrict__ Wu, const float* __restrict__ Wf,
                               const float* __restrict__ Wn, ushortT* __restrict__ pack) {
  int idx = blockIdx.x * blockDim.x + threadIdx.x;
  if (idx < GATE_FRAGS) {
    int lane = idx & 63;
    int kt = (idx >> 6) % 12;
    int gc = idx / (64 * 12);
    int c = gc & 7, g = gc >> 3;
    const float* W = (g == 0) ? Wi : (g == 1) ? Wo : (g == 2) ? Wu : Wf;
    int k0 = kt * 32 + (lane >> 4) * 8;
    int col = c * 16 + (lane & 15);
    ushortT* dst = pack + (size_t)idx * 8;
    #pragma unroll
    for (int j = 0; j < 8; ++j) dst[j] = f2bf(W[(size_t)(k0 + j) * Hc + col]);
  } else if (idx < GATE_FRAGS + WN_FRAGS) {
    int i2 = idx - GATE_FRAGS;
    int lane = i2 & 63;
    int kt = (i2 >> 6) & 7;
    int c = i2 >> 9;
    int k0 = kt * 32 + (lane >> 4) * 8;
    int col = c * 16 + (lane & 15);
    ushortT* dst = pack + (size_t)GATE_FRAGS * 8 + (size_t)i2 * 8;
    #pragma unroll
    for (int j = 0; j < 8; ++j) dst[j] = f2bf(Wn[(size_t)(k0 + j) * Hc + col]);
  }
}

// Wf2 B-fragment (gate pack, g=3, kt=8..11 == Wf rows 256..383)
__device__ __forceinline__ const bf16x8* wf2_frag(const ushortT* pack, int cw, int kf, int lane) {
  return (const bf16x8*)&pack[(size_t)(((3 * 8 + cw) * 12 + (8 + kf)) * 64 + lane) * 8];
}

// ---------------- precompute: passthrough + masked bf16 shadows + Hf = h@Wf2 ----
__global__ __launch_bounds__(256) void precompute(
    const float* __restrict__ h_in, const float* __restrict__ c_in,
    const int* __restrict__ mark, const ushortT* __restrict__ pack,
    float* __restrict__ h_out, float* __restrict__ c_out,
    ushortT* __restrict__ H16, ushortT* __restrict__ C16, ushortT* __restrict__ Hf16,
    int M)
{
  __shared__ __align__(16) ushortT zh[16 * HP];
  __shared__ int mskL[16];
  const int t = threadIdx.x;
  const int row0 = blockIdx.x * 16;

  if (t < 16) mskL[t] = (row0 + t < M) ? (mark[row0 + t] >= 0 ? 1 : 0) : 1;
  __syncthreads();
  {
    int r = t >> 4, cp = t & 15;
    int j = row0 + r;
    bool ok = (j < M);
    int msk = mskL[r];
    float4 a0, a1, b0, b1;
    a0.x=a0.y=a0.z=a0.w=0.f; a1=a0; b0=a0; b1=a0;
    if (ok) {
      const float4* h4 = (const float4*)(h_in + (size_t)j * Hc);
      const float4* c4 = (const float4*)(c_in + (size_t)j * Hc);
      a0 = h4[cp]; a1 = h4[cp + 16]; b0 = c4[cp]; b1 = c4[cp + 16];
      ((float4*)(h_out + (size_t)j * Hc))[cp] = a0;
      ((float4*)(h_out + (size_t)j * Hc))[cp + 16] = a1;
      ((float4*)(c_out + (size_t)j * Hc))[cp] = b0;
      ((float4*)(c_out + (size_t)j * Hc))[cp + 16] = b1;
    }
    us4 zz; zz[0]=zz[1]=zz[2]=zz[3]=0;
    us4 ha0 = msk ? zz : f2bf4(a0), ha1 = msk ? zz : f2bf4(a1);
    us4 ca0 = msk ? zz : f2bf4(b0), ca1 = msk ? zz : f2bf4(b1);
    if (ok) {
      *(us4*)&H16[(size_t)j * Hc + cp * 4] = ha0;
      *(us4*)&H16[(size_t)j * Hc + 64 + cp * 4] = ha1;
      *(us4*)&C16[(size_t)j * Hc + cp * 4] = ca0;
      *(us4*)&C16[(size_t)j * Hc + 64 + cp * 4] = ca1;
    }
    *(us4*)&zh[r * HP + cp * 4] = ha0;
    *(us4*)&zh[r * HP + 64 + cp * 4] = ha1;
  }
  __syncthreads();

  const int w = t >> 6, lane = t & 63, lg = lane >> 4, cl = lane & 15;
  f32x4 acc0 = (f32x4){0.f,0.f,0.f,0.f}, acc1 = acc0;
  const ushortT* zr = &zh[cl * HP + lg * 8];
  #pragma unroll
  for (int kf = 0; kf < 4; ++kf) {
    bf16x8 a = *(const bf16x8*)&zr[kf * 32];
    acc0 = __builtin_amdgcn_mfma_f32_16x16x32_bf16(a, *wf2_frag(pack, w*2+0, kf, lane), acc0, 0, 0, 0);
    acc1 = __builtin_amdgcn_mfma_f32_16x16x32_bf16(a, *wf2_frag(pack, w*2+1, kf, lane), acc1, 0, 0, 0);
  }
  #pragma unroll
  for (int half = 0; half < 2; ++half) {
    int col = (w * 2 + half) * 16 + cl;
    f32x4 a_ = half ? acc1 : acc0;
    #pragma unroll
    for (int reg = 0; reg < 4; ++reg) {
      int j = row0 + lg * 4 + reg;
      if (j < M) Hf16[(size_t)j * Hc + col] = f2bf(a_[reg]);
    }
  }
}

// ---------------- update shadows at sub rows from iter-0 output ----------------
__global__ __launch_bounds__(256) void update_sub(
    const float* __restrict__ h_out, const float* __restrict__ c_out,
    const int* __restrict__ submess, const ushortT* __restrict__ pack,
    ushortT* __restrict__ H16, ushortT* __restrict__ C16, ushortT* __restrict__ Hf16,
    int S)
{
  __shared__ __align__(16) ushortT zh[16 * HP];
  __shared__ int msL[16];
  const int t = threadIdx.x;
  const int row0 = blockIdx.x * 16;

  if (t < 16) msL[t] = (row0 + t < S) ? submess[row0 + t] : -1;
  __syncthreads();
  {
    int r = t >> 4, cp = t & 15;
    int ms = msL[r];
    float4 a0, a1, b0, b1;
    a0.x=a0.y=a0.z=a0.w=0.f; a1=a0; b0=a0; b1=a0;
    if (ms >= 0) {
      const float4* h4 = (const float4*)(h_out + (size_t)ms * Hc);
      const float4* c4 = (const float4*)(c_out + (size_t)ms * Hc);
      a0 = h4[cp]; a1 = h4[cp + 16]; b0 = c4[cp]; b1 = c4[cp + 16];
    }
    us4 ha0 = f2bf4(a0), ha1 = f2bf4(a1);
    if (ms >= 0) {
      *(us4*)&H16[(size_t)ms * Hc + cp * 4] = ha0;
      *(us4*)&H16[(size_t)ms * Hc + 64 + cp * 4] = ha1;
      *(us4*)&C16[(size_t)ms * Hc + cp * 4] = f2bf4(b0);
      *(us4*)&C16[(size_t)ms * Hc + 64 + cp * 4] = f2bf4(b1);
    }
    *(us4*)&zh[r * HP + cp * 4] = ha0;
    *(us4*)&zh[r * HP + 64 + cp * 4] = ha1;
  }
  __syncthreads();

  const int w = t >> 6, lane = t & 63, lg = lane >> 4, cl = lane & 15;
  f32x4 acc0 = (f32x4){0.f,0.f,0.f,0.f}, acc1 = acc0;
  const ushortT* zr = &zh[cl * HP + lg * 8];
  #pragma unroll
  for (int kf = 0; kf < 4; ++kf) {
    bf16x8 a = *(const bf16x8*)&zr[kf * 32];
    acc0 = __builtin_amdgcn_mfma_f32_16x16x32_bf16(a, *wf2_frag(pack, w*2+0, kf, lane), acc0, 0, 0, 0);
    acc1 = __builtin_amdgcn_mfma_f32_16x16x32_bf16(a, *wf2_frag(pack, w*2+1, kf, lane), acc1, 0, 0, 0);
  }
  #pragma unroll
  for (int half = 0; half < 2; ++half) {
    int col = (w * 2 + half) * 16 + cl;
    f32x4 a_ = half ? acc1 : acc0;
    #pragma unroll
    for (int reg = 0; reg < 4; ++reg) {
      int ms = msL[lg * 4 + reg];
      if (ms >= 0) Hf16[(size_t)ms * Hc + col] = f2bf(a_[reg]);
    }
  }
}

// ---------------- LSTM step: gate MFMAs + LDS roundtrip + vectorized epilogue ----
__global__ __launch_bounds__(256) void lstm_step3(
    const float* __restrict__ fmess, const int* __restrict__ submess,
    const int* __restrict__ bgraph,
    const ushortT* __restrict__ H16, const ushortT* __restrict__ C16,
    const ushortT* __restrict__ Hf16,
    const ushortT* __restrict__ pack,
    const float* __restrict__ bi, const float* __restrict__ bo,
    const float* __restrict__ bu, const float* __restrict__ bfb,
    float* __restrict__ dstH, float* __restrict__ dstC, int S)
{
  // union: zs (bf16 [16][ZP] = 12544B) | epilogue f32 arrays cst/osg/fxl [16][EPD]
  __shared__ __align__(16) unsigned char pool[3 * 16 * EPD * 4];   // 25344B
  __shared__ int nbj[16][Kc];
  __shared__ int msrow[16];

  ushortT* zs = (ushortT*)pool;
  float* cst = (float*)pool;
  float* osg = cst + 16 * EPD;
  float* fxl = osg + 16 * EPD;

  const int t = threadIdx.x;
  const int row0 = blockIdx.x * 16;

  if (t < 16) msrow[t] = (row0 + t < S) ? submess[row0 + t] : -1;
  __syncthreads();

  // ---- stage x (bf16) + neighbor ids ----
  {
    int r = t >> 4, cp = t & 15;
    int ms = msrow[r];
    const float4* xr = (ms >= 0) ? (const float4*)(fmess + (size_t)ms * INc) : nullptr;
    #pragma unroll
    for (int q = 0; q < 4; ++q) {
      int slot = cp + q * 16;
      float4 v;
      if (xr) v = xr[slot]; else { v.x = v.y = v.z = v.w = 0.f; }
      *(us4*)&zs[r * ZP + slot * 4] = f2bf4(v);
    }
  }
  if (t < 128) {
    int r = t >> 3, k = t & 7;
    int ms = msrow[r];
    nbj[r][k] = (ms >= 0) ? bgraph[(size_t)ms * Kc + k] : 0;
  }
  __syncthreads();

  // ---- h_sum from bf16 shadow (uniform, vectorized) ----
  {
    int r = t >> 4, cp = t & 15;
    float sum[8] = {0.f,0.f,0.f,0.f,0.f,0.f,0.f,0.f};
    #pragma unroll
    for (int k = 0; k < Kc; ++k) {
      int j = nbj[r][k];
      us8 v = *(const us8*)&H16[(size_t)j * Hc + cp * 8];
      #pragma unroll
      for (int e = 0; e < 8; ++e) sum[e] += bf2f(v[e]);
    }
    us4 o0, o1;
    #pragma unroll
    for (int e = 0; e < 4; ++e) { o0[e] = f2bf(sum[e]); o1[e] = f2bf(sum[4 + e]); }
    *(us4*)&zs[r * ZP + INc + cp * 8] = o0;
    *(us4*)&zs[r * ZP + INc + cp * 8 + 4] = o1;
  }
  __syncthreads();

  const int w = t >> 6, lane = t & 63, lg = lane >> 4, cl = lane & 15;

  // ---- gate K-loop: 88 MFMAs/wave ----
  f32x4 acc[8];
  #pragma unroll
  for (int i = 0; i < 8; ++i) acc[i] = (f32x4){0.f, 0.f, 0.f, 0.f};

  const ushortT* zrow = &zs[cl * ZP + lg * 8];
  const ushortT* bp = pack + (size_t)lane * 8;
  #pragma unroll
  for (int kt = 0; kt < 12; ++kt) {
    bf16x8 a = *(const bf16x8*)&zrow[kt * 32];
    #pragma unroll
    for (int tix = 0; tix < 8; ++tix) {
      int g = tix >> 1;
      if (g == 3 && kt >= 8) continue;
      int cw = w * 2 + (tix & 1);
      bf16x8 b = *(const bf16x8*)(bp + ((size_t)((g * 8 + cw) * 12 + kt)) * 512);
      acc[tix] = __builtin_amdgcn_mfma_f32_16x16x32_bf16(a, b, acc[tix], 0, 0, 0);
    }
  }
  __syncthreads();   // all A-frag reads of zs done; pool may be overwritten

  // ---- write epilogue arrays (biases folded) ----
  #pragma unroll
  for (int half = 0; half < 2; ++half) {
    int col = (w * 2 + half) * 16 + cl;
    float biv = bi[col], bov = bo[col], buv = bu[col], bfv = bfb[col];
    f32x4 ia = acc[0 + half], oa = acc[2 + half], ua = acc[4 + half], fa = acc[6 + half];
    #pragma unroll
    for (int reg = 0; reg < 4; ++reg) {
      int row = lg * 4 + reg;
      cst[row * EPD + col] = fsig(ia[reg] + biv) * ftanh(ua[reg] + buv);
      osg[row * EPD + col] = fsig(oa[reg] + bov);
      fxl[row * EPD + col] = fa[reg] + bfv;
    }
  }
  __syncthreads();

  // ---- finish: (row, 8-col chunk) mapping; vectorized 16B gathers + stores ----
  {
    int r = t >> 4, cc = t & 15;
    int ms = msrow[r];
    float fx[8], ci[8], ov[8], cacc[8];
    {
      const float4* pF = (const float4*)&fxl[r * EPD + cc * 8];
      const float4* pC = (const float4*)&cst[r * EPD + cc * 8];
      const float4* pO = (const float4*)&osg[r * EPD + cc * 8];
      *(float4*)&fx[0] = pF[0]; *(float4*)&fx[4] = pF[1];
      *(float4*)&ci[0] = pC[0]; *(float4*)&ci[4] = pC[1];
      *(float4*)&ov[0] = pO[0]; *(float4*)&ov[4] = pO[1];
    }
    #pragma unroll
    for (int e = 0; e < 8; ++e) cacc[e] = ci[e];
    #pragma unroll
    for (int k = 0; k < Kc; ++k) {
      int j = nbj[r][k];
      us8 hf8 = *(const us8*)&Hf16[(size_t)j * Hc + cc * 8];
      us8 cn8 = *(const us8*)&C16[(size_t)j * Hc + cc * 8];
      #pragma unroll
      for (int e = 0; e < 8; ++e)
        cacc[e] = fmaf(fsig(fx[e] + bf2f(hf8[e])), bf2f(cn8[e]), cacc[e]);
    }
    if (ms >= 0) {
      float hv[8];
      #pragma unroll
      for (int e = 0; e < 8; ++e) hv[e] = ov[e] * ftanh(cacc[e]);
      float* dh = dstH + (size_t)ms * Hc + cc * 8;
      float* dc = dstC + (size_t)ms * Hc + cc * 8;
      *(float4*)&dh[0] = *(float4*)&hv[0];
      *(float4*)&dh[4] = *(float4*)&hv[4];
      *(float4*)&dc[0] = *(float4*)&cacc[0];
      *(float4*)&dc[4] = *(float4*)&cacc[4];
    }
  }
}

// ---------------- node readout (MFMA, unchanged) ----------------
__global__ __launch_bounds__(256) void node_readout_mfma(
    const float* __restrict__ fnode, const int* __restrict__ agraph,
    const int* __restrict__ subnode, const float* __restrict__ hfull,
    const ushortT* __restrict__ packWn, const float* __restrict__ bn,
    float* __restrict__ node_buf, int Nsub)
{
  __shared__ __align__(16) ushortT z2[16 * ZP2];
  __shared__ int orow[16];
  __shared__ const float* aptr[16][Kc];

  const int t = threadIdx.x;
  const int row0 = blockIdx.x * 16;

  if (t < 16) orow[t] = (row0 + t < Nsub) ? subnode[row0 + t] : -1;
  if (t >= 64 && t < 64 + 128) {
    int i = t - 64, r = i >> 3, k = i & 7;
    int v = row0 + r;
    aptr[r][k] = (v < Nsub) ? hfull + (size_t)agraph[(size_t)v * Kc + k] * Hc : nullptr;
  }
  {
    int r = t >> 4, cp = t & 15;
    int v = row0 + r;
    const float4* fr = (v < Nsub) ? (const float4*)(fnode + (size_t)v * Hc) : nullptr;
    float4 v0, v1; v0.x = v0.y = v0.z = v0.w = 0.f; v1 = v0;
    if (fr) { v0 = fr[cp]; v1 = fr[cp + 16]; }
    *(us4*)&z2[r * ZP2 + cp * 4] = f2bf4(v0);
    *(us4*)&z2[r * ZP2 + 64 + cp * 4] = f2bf4(v1);
  }
  __syncthreads();
  {
    int r = t >> 4, cp = t & 15;
    float4 s0, s1; s0.x = s0.y = s0.z = s0.w = 0.f; s1 = s0;
    #pragma unroll
    for (int k = 0; k < Kc; ++k) {
      const float* p = aptr[r][k];
      if (p) {
        float4 v0 = ((const float4*)p)[cp], v1 = ((const float4*)p)[cp + 16];
        s0.x += v0.x; s0.y += v0.y; s0.z += v0.z; s0.w += v0.w;
        s1.x += v1.x; s1.y += v1.y; s1.z += v1.z; s1.w += v1.w;
      }
    }
    *(us4*)&z2[r * ZP2 + Hc + cp * 4] = f2bf4(s0);
    *(us4*)&z2[r * ZP2 + Hc + 64 + cp * 4] = f2bf4(s1);
  }
  __syncthreads();

  const int w = t >> 6, lane = t & 63;
  const int lg = lane >> 4, cl = lane & 15;

  f32x4 acc0 = (f32x4){0.f,0.f,0.f,0.f};
  f32x4 acc1 = (f32x4){0.f,0.f,0.f,0.f};
  const ushortT* zr = &z2[cl * ZP2 + lg * 8];
  #pragma unroll
  for (int kt = 0; kt < 8; ++kt) {
    bf16x8 a = *(const bf16x8*)&zr[kt * 32];
    bf16x8 b0 = *(const bf16x8*)&packWn[(size_t)(((w * 2 + 0) * 8 + kt) * 64 + lane) * 8];
    bf16x8 b1 = *(const bf16x8*)&packWn[(size_t)(((w * 2 + 1) * 8 + kt) * 64 + lane) * 8];
    acc0 = __builtin_amdgcn_mfma_f32_16x16x32_bf16(a, b0, acc0, 0, 0, 0);
    acc1 = __builtin_amdgcn_mfma_f32_16x16x32_bf16(a, b1, acc1, 0, 0, 0);
  }
  #pragma unroll
  for (int half = 0; half < 2; ++half) {
    int col = (w * 2 + half) * 16 + cl;
    float bnv = bn[col];
    f32x4 a_ = half ? acc1 : acc0;
    #pragma unroll
    for (int reg = 0; reg < 4; ++reg) {
      int row = lg * 4 + reg;
      int o = orow[row];
      if (o >= 0) node_buf[(size_t)o * Hc + col] = fmaxf(a_[reg] + bnv, 0.f);
    }
  }
}

// ---------------- launch ----------------
extern "C" void kernel_launch(void* const* d_in, const int* in_sizes, int n_in,
                              void* d_out, int out_size, void* d_ws, size_t ws_size,
                              hipStream_t stream) {
  const float* fnode   = (const float*)d_in[0];
  const float* fmess   = (const float*)d_in[1];
  const int*   agraph  = (const int*)d_in[2];
  const int*   bgraph  = (const int*)d_in[3];
  const float* h_in    = (const float*)d_in[4];
  const float* c_in    = (const float*)d_in[5];
  const int*   submess = (const int*)d_in[6];
  const int*   subnode = (const int*)d_in[7];
  const float* Wi = (const float*)d_in[9];
  const float* bi = (const float*)d_in[10];
  const float* Wo = (const float*)d_in[11];
  const float* bo = (const float*)d_in[12];
  const float* Wf = (const float*)d_in[13];
  const float* bf_ = (const float*)d_in[14];
  const float* Wu = (const float*)d_in[15];
  const float* bu = (const float*)d_in[16];
  const float* Wn = (const float*)d_in[17];
  const float* bn = (const float*)d_in[18];

  const int S    = in_sizes[6];
  const int Nsub = in_sizes[2] / Kc;
  const int M    = in_sizes[4] / Hc;
  const int num_nodes = out_size / Hc - 2 * M;

  float* node_buf = (float*)d_out;
  float* h_out = node_buf + (size_t)num_nodes * Hc;
  float* c_out = h_out + (size_t)M * Hc;

  // ws layout: mark[M] | pack | Hf16[M*128] bf16 | C16[M*128] bf16
  // H16[M*128] bf16 lives in the node_buf region (zeroed only after iter1).
  int* mark = (int*)d_ws;
  size_t off = (((size_t)M * sizeof(int)) + 255) & ~(size_t)255;
  ushortT* pack = (ushortT*)((char*)d_ws + off);
  off += (((size_t)(GATE_FRAGS + WN_FRAGS) * 8 * sizeof(ushortT)) + 255) & ~(size_t)255;
  ushortT* Hf16 = (ushortT*)((char*)d_ws + off);
  off += (((size_t)M * Hc * sizeof(ushortT)) + 255) & ~(size_t)255;
  ushortT* C16 = (ushortT*)((char*)d_ws + off);
  ushortT* H16 = (ushortT*)node_buf;   // 30.7MB <= num_nodes*Hc*4 = 33.5MB
  ushortT* packWn = pack + (size_t)GATE_FRAGS * 8;

  // 1. mark + weight repack
  hipLaunchKernelGGL(mark_init, dim3((M + 255) / 256), dim3(256), 0, stream, mark, M);
  hipLaunchKernelGGL(mark_set,  dim3((S + 255) / 256), dim3(256), 0, stream, mark, submess, S);
  hipLaunchKernelGGL(repack_weights, dim3((GATE_FRAGS + WN_FRAGS + 255) / 256), dim3(256), 0, stream,
                     Wi, Wo, Wu, Wf, Wn, pack);

  // 2. precompute: h/c passthrough + masked bf16 shadows + Hf = masked h @ Wf2
  hipLaunchKernelGGL(precompute, dim3((M + 15) / 16), dim3(256), 0, stream,
                     h_in, c_in, mark, pack, h_out, c_out, H16, C16, Hf16, M);

  const int lblocks = (S + 15) / 16;
  // 3. iter 0
  hipLaunchKernelGGL(lstm_step3, dim3(lblocks), dim3(256), 0, stream,
      fmess, submess, bgraph, H16, C16, Hf16, pack,
      bi, bo, bu, bf_, h_out, c_out, S);
  // 4. refresh shadows at sub rows
  hipLaunchKernelGGL(update_sub, dim3(lblocks), dim3(256), 0, stream,
      h_out, c_out, submess, pack, H16, C16, Hf16, S);
  // 5. iter 1
  hipLaunchKernelGGL(lstm_step3, dim3(lblocks), dim3(256), 0, stream,
      fmess, submess, bgraph, H16, C16, Hf16, pack,
      bi, bo, bu, bf_, h_out, c_out, S);

  // 6. zero node_buf (erases H16 shadow), then node readout
  long nn4 = (long)num_nodes * Hc / 4;
  long zb = (nn4 + 255) / 256; if (zb > 8192) zb = 8192;
  hipLaunchKernelGGL(zero_f4, dim3((int)zb), dim3(256), 0, stream, (float4*)node_buf, nn4);

  const int nblocks = (Nsub + 15) / 16;
  hipLaunchKernelGGL(node_readout_mfma, dim3(nblocks), dim3(256), 0, stream,
      fnode, agraph, subnode, h_out, packWn, bn, node_buf, S);
}